// Round 13
// baseline (133.606 us; speedup 1.0000x reference)
//
#include <hip/hip_runtime.h>

#define B_SZ 8
#define T_LEN 4096
#define N_DIM 256
#define H_DIM 512
#define NC 32
#define CL 128
#define ROWS (B_SZ * T_LEN)

#define BM 128
#define BN 128
#define BKg 32

typedef __attribute__((ext_vector_type(4))) float f32x4;
typedef __attribute__((ext_vector_type(8))) short bf16x8;

static __device__ __forceinline__ unsigned short f2bf(float f) {
    unsigned int u = __float_as_uint(f);
    unsigned int r = (u + 0x7FFFu + ((u >> 16) & 1u)) >> 16;
    return (unsigned short)r;
}
static __device__ __forceinline__ float bf2f(unsigned short s) {
    return __uint_as_float(((unsigned int)s) << 16);
}

static __device__ __forceinline__ void lam_of(const float* __restrict__ nu,
                                              const float* __restrict__ theta,
                                              int h, float& lre, float& lim) {
    float r = __expf(-__expf(nu[h]));
    float th = theta[h];
    lre = r * __cosf(th);
    lim = r * __sinf(th);
}

// ---------- conversion kernels ----------
__global__ __launch_bounds__(256) void conv_x(const float4* __restrict__ x, ushort4* __restrict__ xb) {
    int id = blockIdx.x * 256 + threadIdx.x;
    float4 v = x[id];
    ushort4 o;
    o.x = f2bf(v.x); o.y = f2bf(v.y); o.z = f2bf(v.z); o.w = f2bf(v.w);
    xb[id] = o;
}

// BT1[n][k] (1024 x 256): n=2h -> Bre[k][h], n=2h+1 -> Bim[k][h]
__global__ __launch_bounds__(256) void conv_Bt(const float* __restrict__ Bre,
                                               const float* __restrict__ Bim,
                                               unsigned short* __restrict__ BT1) {
    int id = blockIdx.x * 256 + threadIdx.x;           // id = k*512 + h
    int k = id >> 9, h = id & 511;
    BT1[(long)(2 * h) * 256 + k]     = f2bf(Bre[id]);
    BT1[(long)(2 * h + 1) * 256 + k] = f2bf(Bim[id]);
}

// CT[n][k] (256 x 1024): k=2h -> Cre[h][n], k=2h+1 -> -Cim[h][n]
__global__ __launch_bounds__(256) void conv_Ct(const float* __restrict__ Cre,
                                               const float* __restrict__ Cim,
                                               unsigned short* __restrict__ CT) {
    int id = blockIdx.x * 256 + threadIdx.x;           // id = h*256 + nn
    int h = id >> 8, nn = id & 255;
    CT[(long)nn * 1024 + 2 * h]     = f2bf(Cre[id]);
    CT[(long)nn * 1024 + 2 * h + 1] = f2bf(-Cim[id]);
}

// ---------- MFMA GEMM: out = A(MxK) @ Bt(NxK)^T, bf16 in, f32 acc ----------
// R13 K-loop: ONE barrier per iteration (R2-verified scheme, 128^2 geometry):
//   wait vmcnt(4) [tile t landed for this wave; t+1 still flying]
//   s_barrier     [tile t landed for ALL waves; buffer (t+2)%3=(t-1)%3 was
//                  consumed in iter t-1, whose ds_reads retired before each
//                  wave reached this barrier -> WAR-safe to overwrite]
//   stage(t+2) | ds_read tile t | MFMA      (no second barrier)
// Same write-side/read-side XOR swizzle pair (HW-verified, 0 conflicts).
// Swapped-operand MFMA (R4-verified): lane holds out row=lane&15,
// cols=(lane>>4)*4+r -> vectorized line-coalesced stores.
// R13 MODE0 epilogue: 3-phase, minimal liveness + ONE barrier:
//   1. per n: incremental csum straight from acc (no ur/ui/pk arrays),
//      per-n shfl reduce, fr==0 writes red (=As[0]; safe: all LDS reads
//      retired at the final loop barrier, and the final tile's buffer is
//      As[1] for nt=8 -- red never aliases a live buffer here)
//   2. one __syncthreads; tid<32 gathers + stores sums
//   3. xs stores LAST, recomputed from acc (only s_endpgm waits on them)
// MODE 1: K3 epilogue (add D[col]*u[row][col], store f32); u from e1b (bf16) if non-null else e1 (f32)
template <int MODE>
__global__ __launch_bounds__(256) void gemm_mfma(const unsigned short* __restrict__ A,
                                                 const unsigned short* __restrict__ Bt,
                                                 int M, int N, int K,
                                                 const float* __restrict__ e0,
                                                 const float* __restrict__ e1,
                                                 const unsigned short* __restrict__ e1b,
                                                 const float* __restrict__ nu,
                                                 const float* __restrict__ theta,
                                                 float4* __restrict__ sums,
                                                 void* __restrict__ out) {
    __shared__ __align__(16) unsigned short As[3][BM * BKg];   // 3 x 8 KB
    __shared__ __align__(16) unsigned short Bs[3][BN * BKg];   // 3 x 8 KB
    const int tid = threadIdx.x;
    const int lane = tid & 63;
    const int wave = tid >> 6;
    const int wr = wave >> 1, wc = wave & 1;

    // XCD-aware swizzle (grid % 8 == 0 for both instantiations)
    const int nwg = (int)gridDim.x;
    const int cpx = nwg >> 3;
    const int bid = (int)blockIdx.x;
    const int tile = (bid & 7) * cpx + (bid >> 3);

    const int nTilesN = N / BN;
    const long tileM = (long)(tile / nTilesN) * BM;
    const long tileN = (long)(tile % nTilesN) * BN;

    // staging geometry (per-lane constants).  LDS row r = c*16 + (lane>>2),
    // LDS slot = lane&3 (16B units).  Source k-segment = slot ^ ((r>>1)&3),
    // and (r>>1)&3 == (lane>>3)&3 here.
    const int rsub = lane >> 2;
    const int sg = 8 * ((lane & 3) ^ ((lane >> 3) & 3));    // swizzled k-offset (ushorts)
    const unsigned short* Abase = A + tileM * (long)K + sg;
    const unsigned short* Bbase = Bt + tileN * (long)K + sg;

    auto stage = [&](int buf, int k0) {
#pragma unroll
        for (int cc = 0; cc < 2; ++cc) {
            const int c = wave + cc * 4;
            const int row = c * 16 + rsub;
            const unsigned short* ga = Abase + (long)row * K + k0;
            __builtin_amdgcn_global_load_lds((const __attribute__((address_space(1))) unsigned int*)ga,
                                             (__attribute__((address_space(3))) unsigned int*)(As[buf] + c * 512),
                                             16, 0, 0);
            const unsigned short* gb = Bbase + (long)row * K + k0;
            __builtin_amdgcn_global_load_lds((const __attribute__((address_space(1))) unsigned int*)gb,
                                             (__attribute__((address_space(3))) unsigned int*)(Bs[buf] + c * 512),
                                             16, 0, 0);
        }
    };

    // read-side swizzle: want global k-segment (lane>>4); stored at slot
    // (lane>>4) ^ ((row>>1)&3), and row bits 1-2 == lane bits 1-2.
    const int rdA = 16 * ((lane >> 4) ^ ((lane >> 1) & 3));  // byte offset in row

    f32x4 acc[4][4] = {};
    const int nt = K / BKg;

    stage(0, 0);
    stage(1, BKg);

    int cur = 0, pf = 2;
    for (int t = 0; t < nt; ++t) {
        if (t + 1 < nt) {
            asm volatile("s_waitcnt vmcnt(4)" ::: "memory");   // tile t landed; t+1 flying
        } else {
            asm volatile("s_waitcnt vmcnt(0)" ::: "memory");
        }
        __builtin_amdgcn_s_barrier();                          // RAW + WAR (see header)
        asm volatile("" ::: "memory");

        if (t + 2 < nt) stage(pf, (t + 2) * BKg);

        bf16x8 af[4], bfr[4];
#pragma unroll
        for (int m = 0; m < 4; ++m) {
            const int row = wr * 64 + m * 16 + (lane & 15);
            af[m] = *(const bf16x8*)((const char*)As[cur] + row * 64 + rdA);
        }
#pragma unroll
        for (int n = 0; n < 4; ++n) {
            const int row = wc * 64 + n * 16 + (lane & 15);
            bfr[n] = *(const bf16x8*)((const char*)Bs[cur] + row * 64 + rdA);
        }
        // swapped operands: acc[m][n] holds the TRANSPOSED 16x16 tile:
        // out row = lane&15, out cols = (lane>>4)*4 + r  (r = reg index)
#pragma unroll
        for (int m = 0; m < 4; ++m)
#pragma unroll
            for (int n = 0; n < 4; ++n)
                acc[m][n] = __builtin_amdgcn_mfma_f32_16x16x32_bf16(bfr[n], af[m], acc[m][n], 0, 0, 0);

        asm volatile("" ::: "memory");
        cur = (cur == 2) ? 0 : cur + 1;
        pf = (pf == 2) ? 0 : pf + 1;
    }

    const int fr = lane & 15;
    const int fs = lane >> 4;
    if constexpr (MODE == 0) {
        unsigned short* o = (unsigned short*)out;
        float4* red = (float4*)As;                  // As[0]; final tile used As[1] (nt=8)
        const int pb = 127 - wr * 64 - fr;          // weight exponent base
        const float p3 = (float)(pb - 48);
        // ---- phase 1: csum from acc + per-n reduce (no arrays, low liveness) ----
#pragma unroll
        for (int n = 0; n < 4; ++n) {
            const int col0 = (int)tileN + wc * 64 + n * 16 + fs * 4;   // multiple of 4
            const int h0 = col0 >> 1;
            const float g0 = __expf(e0[h0]);
            const float g1 = __expf(e0[h0 + 1]);
            float sr0, si0, sr1, si1;
            {   // h0: weight ladder, incremental accumulate from acc[m][n][0..1]*g0
                const float e  = __expf(nu[h0]);
                const float th = theta[h0];
                const float r3 = __expf(-p3 * e);
                float w_r = r3 * __cosf(p3 * th);
                float w_i = r3 * __sinf(p3 * th);
                const float r16 = __expf(-16.f * e);
                const float l_r = r16 * __cosf(16.f * th);
                const float l_i = r16 * __sinf(16.f * th);
                float vr = acc[3][n][0] * g0, vi = acc[3][n][1] * g0;
                sr0 = w_r * vr - w_i * vi;
                si0 = w_r * vi + w_i * vr;
#pragma unroll
                for (int m = 2; m >= 0; --m) {
                    const float nwr = w_r * l_r - w_i * l_i;
                    const float nwi = w_r * l_i + w_i * l_r;
                    w_r = nwr; w_i = nwi;
                    vr = acc[m][n][0] * g0; vi = acc[m][n][1] * g0;
                    sr0 += w_r * vr - w_i * vi;
                    si0 += w_r * vi + w_i * vr;
                }
            }
            {   // h0+1
                const float e  = __expf(nu[h0 + 1]);
                const float th = theta[h0 + 1];
                const float r3 = __expf(-p3 * e);
                float w_r = r3 * __cosf(p3 * th);
                float w_i = r3 * __sinf(p3 * th);
                const float r16 = __expf(-16.f * e);
                const float l_r = r16 * __cosf(16.f * th);
                const float l_i = r16 * __sinf(16.f * th);
                float vr = acc[3][n][2] * g1, vi = acc[3][n][3] * g1;
                sr1 = w_r * vr - w_i * vi;
                si1 = w_r * vi + w_i * vr;
#pragma unroll
                for (int m = 2; m >= 0; --m) {
                    const float nwr = w_r * l_r - w_i * l_i;
                    const float nwi = w_r * l_i + w_i * l_r;
                    w_r = nwr; w_i = nwi;
                    vr = acc[m][n][2] * g1; vi = acc[m][n][3] * g1;
                    sr1 += w_r * vr - w_i * vi;
                    si1 += w_r * vi + w_i * vr;
                }
            }
#pragma unroll
            for (int st = 1; st < 16; st <<= 1) {
                sr0 += __shfl_xor(sr0, st);
                si0 += __shfl_xor(si0, st);
                sr1 += __shfl_xor(sr1, st);
                si1 += __shfl_xor(si1, st);
            }
            if (fr == 0)
                red[wr * 32 + wc * 16 + n * 4 + fs] = make_float4(sr0, si0, sr1, si1);
        }
        // ---- phase 2: single barrier + sums store ----
        __syncthreads();
        if (tid < 32) {
            float4 a = red[tid], b2 = red[32 + tid];
            // sums[(b*NC+c)*256 + hp]; (b*NC+c) == tileM/128, hp == tileN/4 + slot
            sums[(long)(tileM >> 7) * 256 + (tileN >> 2) + tid] =
                make_float4(a.x + b2.x, a.y + b2.y, a.z + b2.z, a.w + b2.w);
        }
        // ---- phase 3: xs stores LAST, recomputed from acc ----
#pragma unroll
        for (int n = 0; n < 4; ++n) {
            const int col0 = (int)tileN + wc * 64 + n * 16 + fs * 4;
            const int h0 = col0 >> 1;
            const float g0 = __expf(e0[h0]);
            const float g1 = __expf(e0[h0 + 1]);
#pragma unroll
            for (int m = 0; m < 4; ++m) {
                const long grow = tileM + wr * 64 + m * 16 + fr;
                ushort4 pk;
                pk.x = f2bf(acc[m][n][0] * g0);
                pk.y = f2bf(acc[m][n][1] * g0);
                pk.z = f2bf(acc[m][n][2] * g1);
                pk.w = f2bf(acc[m][n][3] * g1);
                *(ushort4*)(o + grow * N + col0) = pk;                 // 8B line-coalesced
            }
        }
    } else {
        float* o = (float*)out;
#pragma unroll
        for (int n = 0; n < 4; ++n) {
            const int col0 = (int)tileN + wc * 64 + n * 16 + fs * 4;   // multiple of 4
            const float4 dv = *(const float4*)(e0 + col0);
#pragma unroll
            for (int m = 0; m < 4; ++m) {
                const long grow = tileM + wr * 64 + m * 16 + fr;
                const long idx = grow * N + col0;
                float u0, u1, u2, u3;
                if (e1b) {
                    ushort4 ub = *(const ushort4*)(e1b + idx);
                    u0 = bf2f(ub.x); u1 = bf2f(ub.y); u2 = bf2f(ub.z); u3 = bf2f(ub.w);
                } else {
                    float4 uf = *(const float4*)(e1 + idx);
                    u0 = uf.x; u1 = uf.y; u2 = uf.z; u3 = uf.w;
                }
                float4 st;
                st.x = acc[m][n][0] + dv.x * u0;
                st.y = acc[m][n][1] + dv.y * u1;
                st.z = acc[m][n][2] + dv.z * u2;
                st.w = acc[m][n][3] + dv.w * u3;
                *(float4*)(o + idx) = st;                              // 16B line-coalesced
            }
        }
    }
}

// ---------- scan: chunk sums fused into K1; k2b carries, k2ac local scan ----------

// k2b: exclusive scan over chunk sums -> carry (float4-per-hp layout)
__global__ __launch_bounds__(256) void k2b_carry(const float4* __restrict__ sums,
                                                 float4* __restrict__ carry,
                                                 const float* __restrict__ nu,
                                                 const float* __restrict__ theta) {
    const int gid = blockIdx.x * 256 + threadIdx.x;   // 8*256
    const int hp = gid & 255;
    const int b = gid >> 8;
    float lre0, lim0, lre1, lim1;
    lam_of(nu, theta, 2 * hp, lre0, lim0);
    lam_of(nu, theta, 2 * hp + 1, lre1, lim1);
    // lam^CL via 7 complex squarings (CL = 128 = 2^7)
    float p0r = lre0, p0i = lim0, p1r = lre1, p1i = lim1;
#pragma unroll
    for (int i = 0; i < 7; ++i) {
        float t0 = p0r * p0r - p0i * p0i; p0i = 2.f * p0r * p0i; p0r = t0;
        float t1 = p1r * p1r - p1i * p1i; p1i = 2.f * p1r * p1i; p1r = t1;
    }
    float c0r = 0.f, c0i = 0.f, c1r = 0.f, c1i = 0.f;
#pragma unroll
    for (int c = 0; c < NC; ++c) {
        long idx = ((long)b * NC + c) * 256 + hp;
        carry[idx] = make_float4(c0r, c0i, c1r, c1i);
        float4 s = sums[idx];
        float t0 = fmaf(p0r, c0r, fmaf(-p0i, c0i, s.x));
        c0i = fmaf(p0r, c0i, fmaf(p0i, c0r, s.y));
        c0r = t0;
        float t1 = fmaf(p1r, c1r, fmaf(-p1i, c1i, s.z));
        c1i = fmaf(p1r, c1i, fmaf(p1i, c1r, s.w));
        c1r = t1;
    }
}

// k2ac: fused local scan starting from carry -> final xs (one R+W pass, f32 state throughout)
__global__ __launch_bounds__(256) void k2ac_scan(ushort4* __restrict__ xs4,
                                                 const float4* __restrict__ carry,
                                                 const float* __restrict__ nu,
                                                 const float* __restrict__ theta) {
    const int gid = blockIdx.x * 256 + threadIdx.x;   // 8*32*256
    const int hp = gid & 255;
    const int c = (gid >> 8) & (NC - 1);
    const int b = gid >> 13;
    float lre0, lim0, lre1, lim1;
    lam_of(nu, theta, 2 * hp, lre0, lim0);
    lam_of(nu, theta, 2 * hp + 1, lre1, lim1);
    float4 cr = carry[((long)b * NC + c) * 256 + hp];
    float a0r = cr.x, a0i = cr.y, a1r = cr.z, a1i = cr.w;
    long base = ((long)b * T_LEN + (long)c * CL) * 256 + hp;
#pragma unroll 4
    for (int i = 0; i < CL; ++i) {
        ushort4 v = xs4[base + (long)i * 256];
        float u0r = bf2f(v.x), u0i = bf2f(v.y), u1r = bf2f(v.z), u1i = bf2f(v.w);
        float n0r = fmaf(lre0, a0r, fmaf(-lim0, a0i, u0r));
        float n0i = fmaf(lre0, a0i, fmaf(lim0, a0r, u0i));
        float n1r = fmaf(lre1, a1r, fmaf(-lim1, a1i, u1r));
        float n1i = fmaf(lre1, a1i, fmaf(lim1, a1r, u1i));
        a0r = n0r; a0i = n0i; a1r = n1r; a1i = n1i;
        ushort4 o;
        o.x = f2bf(a0r); o.y = f2bf(a0i); o.z = f2bf(a1r); o.w = f2bf(a1i);
        xs4[base + (long)i * 256] = o;
    }
}

extern "C" void kernel_launch(void* const* d_in, const int* in_sizes, int n_in,
                              void* d_out, int out_size, void* d_ws, size_t ws_size,
                              hipStream_t stream) {
    const float* x         = (const float*)d_in[0];
    const float* Bre       = (const float*)d_in[1];
    const float* Bim       = (const float*)d_in[2];
    const float* Cre       = (const float*)d_in[3];
    const float* Cim       = (const float*)d_in[4];
    const float* Dv        = (const float*)d_in[5];
    const float* nu        = (const float*)d_in[6];
    const float* theta     = (const float*)d_in[7];
    const float* gamma_log = (const float*)d_in[8];
    float* y = (float*)d_out;

    // ws layout (R7):
    //   [0, 64MB)      xs (bf16 interleaved re,im)
    //   [64MB, 66MB)   region A: BT1 (0.5MB, dead after K1) -> CT (0.5MB)
    //   [66MB, 68MB)   region B: carry (1MB) | sums (1MB at +1MB)
    //   [68MB, 84MB)   xb (bf16 x) IF ws_size permits, else xb lives in d_out
    const size_t XS_BYTES  = (size_t)ROWS * H_DIM * 4;
    const size_t REG_BYTES = 2u * 1024 * 1024;
    const size_t XB_BYTES  = (size_t)ROWS * N_DIM * 2;
    unsigned short* xs_us = (unsigned short*)d_ws;
    ushort4* xs4   = (ushort4*)d_ws;
    char* regionA  = (char*)d_ws + XS_BYTES;
    char* regionB  = regionA + REG_BYTES;
    unsigned short* BT1 = (unsigned short*)regionA;
    unsigned short* CT  = (unsigned short*)regionA;
    float4*  carry = (float4*)regionB;
    float4*  sums  = (float4*)(regionB + 1024 * 1024);

    const bool xb_in_ws = ws_size >= XS_BYTES + 2 * REG_BYTES + XB_BYTES;
    unsigned short* xb = xb_in_ws ? (unsigned short*)(regionB + REG_BYTES)
                                  : (unsigned short*)d_out;

    conv_x<<<ROWS * N_DIM / 4 / 256, 256, 0, stream>>>((const float4*)x, (ushort4*)xb);
    conv_Bt<<<(N_DIM * H_DIM) / 256, 256, 0, stream>>>(Bre, Bim, BT1);

    // K1: xs = gamma * (u @ Bint) + fused CL=128 chunk sums
    gemm_mfma<0><<<(ROWS / BM) * (1024 / BN), 256, 0, stream>>>(
        xb, BT1, ROWS, 1024, 256, gamma_log, nullptr, nullptr, nu, theta, sums, xs_us);

    // scan: k2s fused into K1; carries then fused local scan
    k2b_carry<<<(B_SZ * 256) / 256, 256, 0, stream>>>(sums, carry, nu, theta);
    k2ac_scan<<<(B_SZ * NC * 256) / 256, 256, 0, stream>>>(xs4, carry, nu, theta);

    // CT overwrites BT1 region (dead after K1)
    conv_Ct<<<(H_DIM * N_DIM) / 256, 256, 0, stream>>>(Cre, Cim, CT);

    // K3: y = Re(xs @ C) + D*u      M=32768 N=256 K=1024
    gemm_mfma<1><<<(ROWS / BM) * (256 / BN), 256, 0, stream>>>(
        xs_us, CT, ROWS, 256, 1024, Dv, x, xb_in_ws ? xb : nullptr, nullptr, nullptr, nullptr, y);
}

// Round 14
// 132.246 us; speedup vs baseline: 1.0103x; 1.0103x over previous
//
#include <hip/hip_runtime.h>

#define B_SZ 8
#define T_LEN 4096
#define N_DIM 256
#define H_DIM 512
#define NC 32
#define CL 128
#define ROWS (B_SZ * T_LEN)

#define BM 128
#define BN 128
#define BKg 32

typedef __attribute__((ext_vector_type(4))) float f32x4;
typedef __attribute__((ext_vector_type(8))) short bf16x8;

static __device__ __forceinline__ unsigned short f2bf(float f) {
    unsigned int u = __float_as_uint(f);
    unsigned int r = (u + 0x7FFFu + ((u >> 16) & 1u)) >> 16;
    return (unsigned short)r;
}
static __device__ __forceinline__ float bf2f(unsigned short s) {
    return __uint_as_float(((unsigned int)s) << 16);
}

static __device__ __forceinline__ void lam_of(const float* __restrict__ nu,
                                              const float* __restrict__ theta,
                                              int h, float& lre, float& lim) {
    float r = __expf(-__expf(nu[h]));
    float th = theta[h];
    lre = r * __cosf(th);
    lim = r * __sinf(th);
}

// weighted 4-row partial of the CL=128 chunk sum for head h (R7-verified):
//   out = sum_m lam^(pb-16m) * (ur[m] + i*ui[m])
static __device__ __forceinline__ void csum4(const float* __restrict__ nu,
                                             const float* __restrict__ theta,
                                             int h, int pb,
                                             const float* ur, const float* ui,
                                             float& outr, float& outi) {
    const float e  = __expf(nu[h]);
    const float th = theta[h];
    const float p3 = (float)(pb - 48);
    const float r3 = __expf(-p3 * e);
    float w_r = r3 * __cosf(p3 * th);
    float w_i = r3 * __sinf(p3 * th);
    const float r16 = __expf(-16.f * e);
    const float l_r = r16 * __cosf(16.f * th);
    const float l_i = r16 * __sinf(16.f * th);
    float sr = w_r * ur[3] - w_i * ui[3];
    float si = w_r * ui[3] + w_i * ur[3];
#pragma unroll
    for (int m = 2; m >= 0; --m) {
        const float nwr = w_r * l_r - w_i * l_i;
        const float nwi = w_r * l_i + w_i * l_r;
        w_r = nwr; w_i = nwi;
        sr += w_r * ur[m] - w_i * ui[m];
        si += w_r * ui[m] + w_i * ur[m];
    }
    outr = sr; outi = si;
}

// ---------- conversion kernels ----------
__global__ __launch_bounds__(256) void conv_x(const float4* __restrict__ x, ushort4* __restrict__ xb) {
    int id = blockIdx.x * 256 + threadIdx.x;
    float4 v = x[id];
    ushort4 o;
    o.x = f2bf(v.x); o.y = f2bf(v.y); o.z = f2bf(v.z); o.w = f2bf(v.w);
    xb[id] = o;
}

// BT1[n][k] (1024 x 256): n=2h -> Bre[k][h], n=2h+1 -> Bim[k][h]
__global__ __launch_bounds__(256) void conv_Bt(const float* __restrict__ Bre,
                                               const float* __restrict__ Bim,
                                               unsigned short* __restrict__ BT1) {
    int id = blockIdx.x * 256 + threadIdx.x;           // id = k*512 + h
    int k = id >> 9, h = id & 511;
    BT1[(long)(2 * h) * 256 + k]     = f2bf(Bre[id]);
    BT1[(long)(2 * h + 1) * 256 + k] = f2bf(Bim[id]);
}

// CT[n][k] (256 x 1024): k=2h -> Cre[h][n], k=2h+1 -> -Cim[h][n]
__global__ __launch_bounds__(256) void conv_Ct(const float* __restrict__ Cre,
                                               const float* __restrict__ Cim,
                                               unsigned short* __restrict__ CT) {
    int id = blockIdx.x * 256 + threadIdx.x;           // id = h*256 + nn
    int h = id >> 8, nn = id & 255;
    CT[(long)nn * 1024 + 2 * h]     = f2bf(Cre[id]);
    CT[(long)nn * 1024 + 2 * h + 1] = f2bf(-Cim[id]);
}

// ---------- R14 K1: B-panel LDS-resident, A direct-to-register, NO in-loop sync ----------
// Block = 128 rows (one scan chunk) x 128 cols; 4 waves 2x2 (R7 wave geometry,
// so the fused-sums epilogue is R7-verbatim).  B-slice (128 x 256 = 64 KB)
// loaded ONCE via global_load_lds with pre-permuted source, then ONE
// __syncthreads (vmcnt0 drain -- race-proof, no counted vmcnt anywhere).
// K-loop: 8 fully-unrolled kc steps of {4 direct-global A bf16x8 loads +
// 4 ds_read_b128 + 16 MFMA}, zero barriers -- waves free-run; MFMA:global
// = 4:1 (vs R3's 2:1), B from LDS not L2.
// Bank swizzle (NEW, 3-bit, non-overlapping field): global k-slot s stored at
// slot s ^ ((row&7)<<2).  Read slot = (kc*4+fs) ^ ((fr&7)<<2): collisions only
// between lanes fr and fr+8 (same fs) -> exactly 2-way = free (m136).
// (R5's failure: 2-bit XOR overlapped the fs bits -> 8-way.)
__global__ __launch_bounds__(256) void gemm_k1b(const unsigned short* __restrict__ A,
                                                const unsigned short* __restrict__ Bt,
                                                const float* __restrict__ e0,
                                                const float* __restrict__ nu,
                                                const float* __restrict__ theta,
                                                float4* __restrict__ sums,
                                                unsigned short* __restrict__ out) {
    __shared__ __align__(16) unsigned short Bs[128 * 256];   // 64 KB, 512 B/row
    const int tid = threadIdx.x;
    const int lane = tid & 63;
    const int wave = tid >> 6;
    const int wr = wave >> 1, wc = wave & 1;

    // XCD-aware swizzle (grid = 2048, % 8 == 0)
    const int nwg = (int)gridDim.x;
    const int cpx = nwg >> 3;
    const int bid = (int)blockIdx.x;
    const int tile = (bid & 7) * cpx + (bid >> 3);
    const long tileM = (long)(tile >> 3) * BM;      // nTilesN = 8
    const long tileN = (long)(tile & 7) * BN;

    // ---- B panel load (once): 64 units x 1KB; unit u covers rows 2u,2u+1 ----
    // lane l: row = 2u + (l>>5), dest slot = l&31 (16B units, linear).
    // Stored content must be global slot (l&31) ^ ((row&7)<<2)  [write side].
    const int l5 = lane >> 5;
    const int s_lin = lane & 31;
#pragma unroll
    for (int i = 0; i < 16; ++i) {
        const int u = wave * 16 + i;
        const int row = 2 * u + l5;
        const int sg = 8 * (s_lin ^ ((row & 7) << 2));       // ushorts
        const unsigned short* gb = Bt + (tileN + row) * 256L + sg;
        __builtin_amdgcn_global_load_lds((const __attribute__((address_space(1))) unsigned int*)gb,
                                         (__attribute__((address_space(3))) unsigned int*)(Bs + u * 512),
                                         16, 0, 0);
    }
    __syncthreads();                                 // vmcnt(0) drain + barrier (only sync)

    const int fr = lane & 15;
    const int fs = lane >> 4;
    const int bxr = (fr & 7) << 2;                   // read-side XOR (slot units)

    f32x4 acc[4][4] = {};
    const unsigned short* Ab = A + (tileM + wr * 64 + fr) * 256L + fs * 8;

#pragma unroll
    for (int kc = 0; kc < 8; ++kc) {
        bf16x8 af[4], bfr[4];
#pragma unroll
        for (int m = 0; m < 4; ++m)
            af[m] = *(const bf16x8*)(Ab + (long)m * 16 * 256 + kc * 32);
#pragma unroll
        for (int n = 0; n < 4; ++n) {
            const int row = wc * 64 + n * 16 + fr;
            bfr[n] = *(const bf16x8*)((const char*)Bs + row * 512 + 16 * ((kc * 4 + fs) ^ bxr));
        }
        // swapped operands (R4-verified): lane holds out row=fr, cols=fs*4+r
#pragma unroll
        for (int m = 0; m < 4; ++m)
#pragma unroll
            for (int n = 0; n < 4; ++n)
                acc[m][n] = __builtin_amdgcn_mfma_f32_16x16x32_bf16(bfr[n], af[m], acc[m][n], 0, 0, 0);
    }

    // ---- epilogue: R7 MODE0 verbatim (red buffer = Bs) ----
    unsigned short* o = out;
    float s_r0[4], s_i0[4], s_r1[4], s_i1[4];
    const int pb = 127 - wr * 64 - fr;
#pragma unroll
    for (int n = 0; n < 4; ++n) {
        const int col0 = (int)tileN + wc * 64 + n * 16 + fs * 4;
        const int h0 = col0 >> 1;
        const float g0 = __expf(e0[h0]);
        const float g1 = __expf(e0[h0 + 1]);
        float ur0[4], ui0[4], ur1[4], ui1[4];
#pragma unroll
        for (int m = 0; m < 4; ++m) {
            const long grow = tileM + wr * 64 + m * 16 + fr;
            const float v0 = acc[m][n][0] * g0;
            const float v1 = acc[m][n][1] * g0;
            const float v2 = acc[m][n][2] * g1;
            const float v3 = acc[m][n][3] * g1;
            ushort4 pk;
            pk.x = f2bf(v0); pk.y = f2bf(v1); pk.z = f2bf(v2); pk.w = f2bf(v3);
            *(ushort4*)(o + grow * 1024 + col0) = pk;
            ur0[m] = v0; ui0[m] = v1; ur1[m] = v2; ui1[m] = v3;
        }
        csum4(nu, theta, h0,     pb, ur0, ui0, s_r0[n], s_i0[n]);
        csum4(nu, theta, h0 + 1, pb, ur1, ui1, s_r1[n], s_i1[n]);
    }
#pragma unroll
    for (int n = 0; n < 4; ++n) {
#pragma unroll
        for (int st = 1; st < 16; st <<= 1) {
            s_r0[n] += __shfl_xor(s_r0[n], st);
            s_i0[n] += __shfl_xor(s_i0[n], st);
            s_r1[n] += __shfl_xor(s_r1[n], st);
            s_i1[n] += __shfl_xor(s_i1[n], st);
        }
    }
    __syncthreads();                        // all ds_reads of Bs retired -> reuse as red
    float4* red = (float4*)Bs;
    if (fr == 0) {
#pragma unroll
        for (int n = 0; n < 4; ++n)
            red[wr * 32 + wc * 16 + n * 4 + fs] = make_float4(s_r0[n], s_i0[n], s_r1[n], s_i1[n]);
    }
    __syncthreads();
    if (tid < 32) {
        float4 a = red[tid], b2 = red[32 + tid];
        sums[(long)(tileM >> 7) * 256 + (tileN >> 2) + tid] =
            make_float4(a.x + b2.x, a.y + b2.y, a.z + b2.z, a.w + b2.w);
    }
}

// ---------- K3: R7 gemm_mfma MODE1 verbatim (3-buffer counted-vmcnt pipeline) ----------
template <int MODE>
__global__ __launch_bounds__(256) void gemm_mfma(const unsigned short* __restrict__ A,
                                                 const unsigned short* __restrict__ Bt,
                                                 int M, int N, int K,
                                                 const float* __restrict__ e0,
                                                 const float* __restrict__ e1,
                                                 const unsigned short* __restrict__ e1b,
                                                 void* __restrict__ out) {
    __shared__ __align__(16) unsigned short As[3][BM * BKg];   // 3 x 8 KB
    __shared__ __align__(16) unsigned short Bs[3][BN * BKg];   // 3 x 8 KB
    const int tid = threadIdx.x;
    const int lane = tid & 63;
    const int wave = tid >> 6;
    const int wr = wave >> 1, wc = wave & 1;

    const int nwg = (int)gridDim.x;
    const int cpx = nwg >> 3;
    const int bid = (int)blockIdx.x;
    const int tile = (bid & 7) * cpx + (bid >> 3);

    const int nTilesN = N / BN;
    const long tileM = (long)(tile / nTilesN) * BM;
    const long tileN = (long)(tile % nTilesN) * BN;

    const int rsub = lane >> 2;
    const int sg = 8 * ((lane & 3) ^ ((lane >> 3) & 3));    // swizzled k-offset (ushorts)
    const unsigned short* Abase = A + tileM * (long)K + sg;
    const unsigned short* Bbase = Bt + tileN * (long)K + sg;

    auto stage = [&](int buf, int k0) {
#pragma unroll
        for (int cc = 0; cc < 2; ++cc) {
            const int c = wave + cc * 4;
            const int row = c * 16 + rsub;
            const unsigned short* ga = Abase + (long)row * K + k0;
            __builtin_amdgcn_global_load_lds((const __attribute__((address_space(1))) unsigned int*)ga,
                                             (__attribute__((address_space(3))) unsigned int*)(As[buf] + c * 512),
                                             16, 0, 0);
            const unsigned short* gb = Bbase + (long)row * K + k0;
            __builtin_amdgcn_global_load_lds((const __attribute__((address_space(1))) unsigned int*)gb,
                                             (__attribute__((address_space(3))) unsigned int*)(Bs[buf] + c * 512),
                                             16, 0, 0);
        }
    };

    const int rdA = 16 * ((lane >> 4) ^ ((lane >> 1) & 3));  // read-side swizzle (byte)

    f32x4 acc[4][4] = {};
    const int nt = K / BKg;

    stage(0, 0);
    stage(1, BKg);

    int cur = 0, pf = 2;
    for (int t = 0; t < nt; ++t) {
        if (t + 2 < nt) {
            stage(pf, (t + 2) * BKg);
            asm volatile("s_waitcnt vmcnt(8)" ::: "memory");
        } else if (t + 1 < nt) {
            asm volatile("s_waitcnt vmcnt(4)" ::: "memory");
        } else {
            asm volatile("s_waitcnt vmcnt(0)" ::: "memory");
        }
        __builtin_amdgcn_s_barrier();
        asm volatile("" ::: "memory");

        bf16x8 af[4], bfr[4];
#pragma unroll
        for (int m = 0; m < 4; ++m) {
            const int row = wr * 64 + m * 16 + (lane & 15);
            af[m] = *(const bf16x8*)((const char*)As[cur] + row * 64 + rdA);
        }
#pragma unroll
        for (int n = 0; n < 4; ++n) {
            const int row = wc * 64 + n * 16 + (lane & 15);
            bfr[n] = *(const bf16x8*)((const char*)Bs[cur] + row * 64 + rdA);
        }
#pragma unroll
        for (int m = 0; m < 4; ++m)
#pragma unroll
            for (int n = 0; n < 4; ++n)
                acc[m][n] = __builtin_amdgcn_mfma_f32_16x16x32_bf16(bfr[n], af[m], acc[m][n], 0, 0, 0);

        asm volatile("" ::: "memory");
        __builtin_amdgcn_s_barrier();
        asm volatile("" ::: "memory");

        cur = (cur == 2) ? 0 : cur + 1;
        pf = (pf == 2) ? 0 : pf + 1;
    }

    const int fr = lane & 15;
    const int fs = lane >> 4;
    {
        float* o = (float*)out;
#pragma unroll
        for (int n = 0; n < 4; ++n) {
            const int col0 = (int)tileN + wc * 64 + n * 16 + fs * 4;
            const float4 dv = *(const float4*)(e0 + col0);
#pragma unroll
            for (int m = 0; m < 4; ++m) {
                const long grow = tileM + wr * 64 + m * 16 + fr;
                const long idx = grow * N + col0;
                float u0, u1, u2, u3;
                if (e1b) {
                    ushort4 ub = *(const ushort4*)(e1b + idx);
                    u0 = bf2f(ub.x); u1 = bf2f(ub.y); u2 = bf2f(ub.z); u3 = bf2f(ub.w);
                } else {
                    float4 uf = *(const float4*)(e1 + idx);
                    u0 = uf.x; u1 = uf.y; u2 = uf.z; u3 = uf.w;
                }
                float4 st;
                st.x = acc[m][n][0] + dv.x * u0;
                st.y = acc[m][n][1] + dv.y * u1;
                st.z = acc[m][n][2] + dv.z * u2;
                st.w = acc[m][n][3] + dv.w * u3;
                *(float4*)(o + idx) = st;
            }
        }
    }
}

// ---------- scan: chunk sums fused into K1; k2b carries, k2ac local scan ----------

// k2b: exclusive scan over chunk sums -> carry (float4-per-hp layout)
__global__ __launch_bounds__(256) void k2b_carry(const float4* __restrict__ sums,
                                                 float4* __restrict__ carry,
                                                 const float* __restrict__ nu,
                                                 const float* __restrict__ theta) {
    const int gid = blockIdx.x * 256 + threadIdx.x;   // 8*256
    const int hp = gid & 255;
    const int b = gid >> 8;
    float lre0, lim0, lre1, lim1;
    lam_of(nu, theta, 2 * hp, lre0, lim0);
    lam_of(nu, theta, 2 * hp + 1, lre1, lim1);
    // lam^CL via 7 complex squarings (CL = 128 = 2^7)
    float p0r = lre0, p0i = lim0, p1r = lre1, p1i = lim1;
#pragma unroll
    for (int i = 0; i < 7; ++i) {
        float t0 = p0r * p0r - p0i * p0i; p0i = 2.f * p0r * p0i; p0r = t0;
        float t1 = p1r * p1r - p1i * p1i; p1i = 2.f * p1r * p1i; p1r = t1;
    }
    float c0r = 0.f, c0i = 0.f, c1r = 0.f, c1i = 0.f;
#pragma unroll
    for (int c = 0; c < NC; ++c) {
        long idx = ((long)b * NC + c) * 256 + hp;
        carry[idx] = make_float4(c0r, c0i, c1r, c1i);
        float4 s = sums[idx];
        float t0 = fmaf(p0r, c0r, fmaf(-p0i, c0i, s.x));
        c0i = fmaf(p0r, c0i, fmaf(p0i, c0r, s.y));
        c0r = t0;
        float t1 = fmaf(p1r, c1r, fmaf(-p1i, c1i, s.z));
        c1i = fmaf(p1r, c1i, fmaf(p1i, c1r, s.w));
        c1r = t1;
    }
}

// k2ac: fused local scan starting from carry -> final xs (one R+W pass, f32 state throughout)
__global__ __launch_bounds__(256) void k2ac_scan(ushort4* __restrict__ xs4,
                                                 const float4* __restrict__ carry,
                                                 const float* __restrict__ nu,
                                                 const float* __restrict__ theta) {
    const int gid = blockIdx.x * 256 + threadIdx.x;   // 8*32*256
    const int hp = gid & 255;
    const int c = (gid >> 8) & (NC - 1);
    const int b = gid >> 13;
    float lre0, lim0, lre1, lim1;
    lam_of(nu, theta, 2 * hp, lre0, lim0);
    lam_of(nu, theta, 2 * hp + 1, lre1, lim1);
    float4 cr = carry[((long)b * NC + c) * 256 + hp];
    float a0r = cr.x, a0i = cr.y, a1r = cr.z, a1i = cr.w;
    long base = ((long)b * T_LEN + (long)c * CL) * 256 + hp;
#pragma unroll 4
    for (int i = 0; i < CL; ++i) {
        ushort4 v = xs4[base + (long)i * 256];
        float u0r = bf2f(v.x), u0i = bf2f(v.y), u1r = bf2f(v.z), u1i = bf2f(v.w);
        float n0r = fmaf(lre0, a0r, fmaf(-lim0, a0i, u0r));
        float n0i = fmaf(lre0, a0i, fmaf(lim0, a0r, u0i));
        float n1r = fmaf(lre1, a1r, fmaf(-lim1, a1i, u1r));
        float n1i = fmaf(lre1, a1i, fmaf(lim1, a1r, u1i));
        a0r = n0r; a0i = n0i; a1r = n1r; a1i = n1i;
        ushort4 o;
        o.x = f2bf(a0r); o.y = f2bf(a0i); o.z = f2bf(a1r); o.w = f2bf(a1i);
        xs4[base + (long)i * 256] = o;
    }
}

extern "C" void kernel_launch(void* const* d_in, const int* in_sizes, int n_in,
                              void* d_out, int out_size, void* d_ws, size_t ws_size,
                              hipStream_t stream) {
    const float* x         = (const float*)d_in[0];
    const float* Bre       = (const float*)d_in[1];
    const float* Bim       = (const float*)d_in[2];
    const float* Cre       = (const float*)d_in[3];
    const float* Cim       = (const float*)d_in[4];
    const float* Dv        = (const float*)d_in[5];
    const float* nu        = (const float*)d_in[6];
    const float* theta     = (const float*)d_in[7];
    const float* gamma_log = (const float*)d_in[8];
    float* y = (float*)d_out;

    // ws layout (R7):
    //   [0, 64MB)      xs (bf16 interleaved re,im)
    //   [64MB, 66MB)   region A: BT1 (0.5MB, dead after K1) -> CT (0.5MB)
    //   [66MB, 68MB)   region B: carry (1MB) | sums (1MB at +1MB)
    //   [68MB, 84MB)   xb (bf16 x) IF ws_size permits, else xb lives in d_out
    const size_t XS_BYTES  = (size_t)ROWS * H_DIM * 4;
    const size_t REG_BYTES = 2u * 1024 * 1024;
    const size_t XB_BYTES  = (size_t)ROWS * N_DIM * 2;
    unsigned short* xs_us = (unsigned short*)d_ws;
    ushort4* xs4   = (ushort4*)d_ws;
    char* regionA  = (char*)d_ws + XS_BYTES;
    char* regionB  = regionA + REG_BYTES;
    unsigned short* BT1 = (unsigned short*)regionA;
    unsigned short* CT  = (unsigned short*)regionA;
    float4*  carry = (float4*)regionB;
    float4*  sums  = (float4*)(regionB + 1024 * 1024);

    const bool xb_in_ws = ws_size >= XS_BYTES + 2 * REG_BYTES + XB_BYTES;
    unsigned short* xb = xb_in_ws ? (unsigned short*)(regionB + REG_BYTES)
                                  : (unsigned short*)d_out;

    conv_x<<<ROWS * N_DIM / 4 / 256, 256, 0, stream>>>((const float4*)x, (ushort4*)xb);
    conv_Bt<<<(N_DIM * H_DIM) / 256, 256, 0, stream>>>(Bre, Bim, BT1);

    // K1 (R14): B-resident, no in-loop sync, fused CL=128 chunk sums
    gemm_k1b<<<(ROWS / BM) * (1024 / BN), 256, 0, stream>>>(
        xb, BT1, gamma_log, nu, theta, sums, xs_us);

    // scan: k2s fused into K1; carries then fused local scan
    k2b_carry<<<(B_SZ * 256) / 256, 256, 0, stream>>>(sums, carry, nu, theta);
    k2ac_scan<<<(B_SZ * NC * 256) / 256, 256, 0, stream>>>(xs4, carry, nu, theta);

    // CT overwrites BT1 region (dead after K1)
    conv_Ct<<<(H_DIM * N_DIM) / 256, 256, 0, stream>>>(Cre, Cim, CT);

    // K3: y = Re(xs @ C) + D*u      M=32768 N=256 K=1024   (R7 verbatim)
    gemm_mfma<1><<<(ROWS / BM) * (256 / BN), 256, 0, stream>>>(
        xs_us, CT, ROWS, 256, 1024, Dv, x, xb_in_ws ? xb : nullptr, y);
}

// Round 15
// 122.822 us; speedup vs baseline: 1.0878x; 1.0767x over previous
//
#include <hip/hip_runtime.h>

#define B_SZ 8
#define T_LEN 4096
#define N_DIM 256
#define H_DIM 512
#define NC 32
#define CL 128
#define ROWS (B_SZ * T_LEN)

#define BM 128
#define BN 128
#define BKg 32

typedef __attribute__((ext_vector_type(4))) float f32x4;
typedef __attribute__((ext_vector_type(8))) short bf16x8;

static __device__ __forceinline__ unsigned short f2bf(float f) {
    unsigned int u = __float_as_uint(f);
    unsigned int r = (u + 0x7FFFu + ((u >> 16) & 1u)) >> 16;
    return (unsigned short)r;
}
static __device__ __forceinline__ float bf2f(unsigned short s) {
    return __uint_as_float(((unsigned int)s) << 16);
}

static __device__ __forceinline__ void lam_of(const float* __restrict__ nu,
                                              const float* __restrict__ theta,
                                              int h, float& lre, float& lim) {
    float r = __expf(-__expf(nu[h]));
    float th = theta[h];
    lre = r * __cosf(th);
    lim = r * __sinf(th);
}

// weighted 4-row partial of the chunk sum for head h:
//   out = sum_m lam^(pb-16m) * (ur[m] + i*ui[m]),  lam = exp(-e^nu[h] + i*theta[h])
static __device__ __forceinline__ void csum4(const float* __restrict__ nu,
                                             const float* __restrict__ theta,
                                             int h, int pb,
                                             const float* ur, const float* ui,
                                             float& outr, float& outi) {
    const float e  = __expf(nu[h]);
    const float th = theta[h];
    const float p3 = (float)(pb - 48);
    const float r3 = __expf(-p3 * e);
    float w_r = r3 * __cosf(p3 * th);
    float w_i = r3 * __sinf(p3 * th);
    const float r16 = __expf(-16.f * e);
    const float l_r = r16 * __cosf(16.f * th);
    const float l_i = r16 * __sinf(16.f * th);
    float sr = w_r * ur[3] - w_i * ui[3];
    float si = w_r * ui[3] + w_i * ur[3];
#pragma unroll
    for (int m = 2; m >= 0; --m) {
        const float nwr = w_r * l_r - w_i * l_i;
        const float nwi = w_r * l_i + w_i * l_r;
        w_r = nwr; w_i = nwi;
        sr += w_r * ur[m] - w_i * ui[m];
        si += w_r * ui[m] + w_i * ur[m];
    }
    outr = sr; outi = si;
}

// ---------- conversion kernels ----------
__global__ __launch_bounds__(256) void conv_x(const float4* __restrict__ x, ushort4* __restrict__ xb) {
    int id = blockIdx.x * 256 + threadIdx.x;
    float4 v = x[id];
    ushort4 o;
    o.x = f2bf(v.x); o.y = f2bf(v.y); o.z = f2bf(v.z); o.w = f2bf(v.w);
    xb[id] = o;
}

// BT1[n][k] (1024 x 256): n=2h -> Bre[k][h], n=2h+1 -> Bim[k][h]
__global__ __launch_bounds__(256) void conv_Bt(const float* __restrict__ Bre,
                                               const float* __restrict__ Bim,
                                               unsigned short* __restrict__ BT1) {
    int id = blockIdx.x * 256 + threadIdx.x;           // id = k*512 + h
    int k = id >> 9, h = id & 511;
    BT1[(long)(2 * h) * 256 + k]     = f2bf(Bre[id]);
    BT1[(long)(2 * h + 1) * 256 + k] = f2bf(Bim[id]);
}

// CT[n][k] (256 x 1024): k=2h -> Cre[h][n], k=2h+1 -> -Cim[h][n]
__global__ __launch_bounds__(256) void conv_Ct(const float* __restrict__ Cre,
                                               const float* __restrict__ Cim,
                                               unsigned short* __restrict__ CT) {
    int id = blockIdx.x * 256 + threadIdx.x;           // id = h*256 + nn
    int h = id >> 8, nn = id & 255;
    CT[(long)nn * 1024 + 2 * h]     = f2bf(Cre[id]);
    CT[(long)nn * 1024 + 2 * h + 1] = f2bf(-Cim[id]);
}

// ---------- MFMA GEMM: out = A(MxK) @ Bt(NxK)^T, bf16 in, f32 acc ----------
// R7 (session best, 121.2us): 3 LDS buffers, depth-2 counted-vmcnt pipeline,
// RAW s_barrier, write-side XOR swizzle via pre-permuted global source +
// matching read-side XOR (0 bank conflicts, HW-verified).  Swapped-operand
// MFMA (lane holds row=lane&15, cols=(lane>>4)*4+r) -> vectorized
// line-coalesced epilogue stores.  MODE 0 fuses the scan's chunk-sum pass
// (k2s): per-lane csum4 over the f32 accumulators, fr-group shfl reduce,
// cross-wave add via dead LDS, one float4 store per h-pair -> deletes the
// 64MB xs re-read.
// MODE 0: K1 epilogue (scale by gamma, store bf16 xs, emit chunk sums)
// MODE 1: K3 epilogue (add D[col]*u[row][col], store f32); u from e1b (bf16) if non-null else e1 (f32)
template <int MODE>
__global__ __launch_bounds__(256) void gemm_mfma(const unsigned short* __restrict__ A,
                                                 const unsigned short* __restrict__ Bt,
                                                 int M, int N, int K,
                                                 const float* __restrict__ e0,
                                                 const float* __restrict__ e1,
                                                 const unsigned short* __restrict__ e1b,
                                                 const float* __restrict__ nu,
                                                 const float* __restrict__ theta,
                                                 float4* __restrict__ sums,
                                                 void* __restrict__ out) {
    __shared__ __align__(16) unsigned short As[3][BM * BKg];   // 3 x 8 KB
    __shared__ __align__(16) unsigned short Bs[3][BN * BKg];   // 3 x 8 KB
    const int tid = threadIdx.x;
    const int lane = tid & 63;
    const int wave = tid >> 6;
    const int wr = wave >> 1, wc = wave & 1;

    // XCD-aware swizzle (grid % 8 == 0 for both instantiations)
    const int nwg = (int)gridDim.x;
    const int cpx = nwg >> 3;
    const int bid = (int)blockIdx.x;
    const int tile = (bid & 7) * cpx + (bid >> 3);

    const int nTilesN = N / BN;
    const long tileM = (long)(tile / nTilesN) * BM;
    const long tileN = (long)(tile % nTilesN) * BN;

    // staging geometry (per-lane constants).  LDS row r = c*16 + (lane>>2),
    // LDS slot = lane&3 (16B units).  Source k-segment = slot ^ ((r>>1)&3),
    // and (r>>1)&3 == (lane>>3)&3 here.
    const int rsub = lane >> 2;
    const int sg = 8 * ((lane & 3) ^ ((lane >> 3) & 3));    // swizzled k-offset (ushorts)
    const unsigned short* Abase = A + tileM * (long)K + sg;
    const unsigned short* Bbase = Bt + tileN * (long)K + sg;

    auto stage = [&](int buf, int k0) {
#pragma unroll
        for (int cc = 0; cc < 2; ++cc) {
            const int c = wave + cc * 4;
            const int row = c * 16 + rsub;
            const unsigned short* ga = Abase + (long)row * K + k0;
            __builtin_amdgcn_global_load_lds((const __attribute__((address_space(1))) unsigned int*)ga,
                                             (__attribute__((address_space(3))) unsigned int*)(As[buf] + c * 512),
                                             16, 0, 0);
            const unsigned short* gb = Bbase + (long)row * K + k0;
            __builtin_amdgcn_global_load_lds((const __attribute__((address_space(1))) unsigned int*)gb,
                                             (__attribute__((address_space(3))) unsigned int*)(Bs[buf] + c * 512),
                                             16, 0, 0);
        }
    };

    // read-side swizzle: want global k-segment (lane>>4); stored at slot
    // (lane>>4) ^ ((row>>1)&3), and row bits 1-2 == lane bits 1-2.
    const int rdA = 16 * ((lane >> 4) ^ ((lane >> 1) & 3));  // byte offset in row

    f32x4 acc[4][4] = {};
    const int nt = K / BKg;

    stage(0, 0);
    stage(1, BKg);

    int cur = 0, pf = 2;
    for (int t = 0; t < nt; ++t) {
        if (t + 2 < nt) {
            stage(pf, (t + 2) * BKg);
            asm volatile("s_waitcnt vmcnt(8)" ::: "memory");   // tile t's 4 glls done
        } else if (t + 1 < nt) {
            asm volatile("s_waitcnt vmcnt(4)" ::: "memory");
        } else {
            asm volatile("s_waitcnt vmcnt(0)" ::: "memory");
        }
        __builtin_amdgcn_s_barrier();                          // all waves: tile t resident
        asm volatile("" ::: "memory");

        bf16x8 af[4], bfr[4];
#pragma unroll
        for (int m = 0; m < 4; ++m) {
            const int row = wr * 64 + m * 16 + (lane & 15);
            af[m] = *(const bf16x8*)((const char*)As[cur] + row * 64 + rdA);
        }
#pragma unroll
        for (int n = 0; n < 4; ++n) {
            const int row = wc * 64 + n * 16 + (lane & 15);
            bfr[n] = *(const bf16x8*)((const char*)Bs[cur] + row * 64 + rdA);
        }
        // swapped operands: acc[m][n] holds the TRANSPOSED 16x16 tile:
        // out row = lane&15, out cols = (lane>>4)*4 + r  (r = reg index)
#pragma unroll
        for (int m = 0; m < 4; ++m)
#pragma unroll
            for (int n = 0; n < 4; ++n)
                acc[m][n] = __builtin_amdgcn_mfma_f32_16x16x32_bf16(bfr[n], af[m], acc[m][n], 0, 0, 0);

        asm volatile("" ::: "memory");
        __builtin_amdgcn_s_barrier();                          // reads of buf cur retired
        asm volatile("" ::: "memory");

        cur = (cur == 2) ? 0 : cur + 1;
        pf = (pf == 2) ? 0 : pf + 1;
    }

    const int fr = lane & 15;
    const int fs = lane >> 4;
    if constexpr (MODE == 0) {
        unsigned short* o = (unsigned short*)out;
        float s_r0[4], s_i0[4], s_r1[4], s_i1[4];
        const int pb = 127 - wr * 64 - fr;                     // weight exponent base
#pragma unroll
        for (int n = 0; n < 4; ++n) {
            const int col0 = (int)tileN + wc * 64 + n * 16 + fs * 4;   // multiple of 4
            const int h0 = col0 >> 1;                                  // cols (col0,col0+1)->h0, (+2,+3)->h0+1
            const float g0 = __expf(e0[h0]);
            const float g1 = __expf(e0[h0 + 1]);
            float ur0[4], ui0[4], ur1[4], ui1[4];
#pragma unroll
            for (int m = 0; m < 4; ++m) {
                const long grow = tileM + wr * 64 + m * 16 + fr;
                const float v0 = acc[m][n][0] * g0;
                const float v1 = acc[m][n][1] * g0;
                const float v2 = acc[m][n][2] * g1;
                const float v3 = acc[m][n][3] * g1;
                ushort4 pk;
                pk.x = f2bf(v0); pk.y = f2bf(v1); pk.z = f2bf(v2); pk.w = f2bf(v3);
                *(ushort4*)(o + grow * N + col0) = pk;                 // 8B store, line-coalesced
                ur0[m] = v0; ui0[m] = v1; ur1[m] = v2; ui1[m] = v3;
            }
            // fused k2s: per-lane weighted partial over this lane's 4 rows
            csum4(nu, theta, h0,     pb, ur0, ui0, s_r0[n], s_i0[n]);
            csum4(nu, theta, h0 + 1, pb, ur1, ui1, s_r1[n], s_i1[n]);
        }
        // reduce over the 16-lane fr-group (lanes fs*16 .. fs*16+15)
#pragma unroll
        for (int n = 0; n < 4; ++n) {
#pragma unroll
            for (int st = 1; st < 16; st <<= 1) {
                s_r0[n] += __shfl_xor(s_r0[n], st);
                s_i0[n] += __shfl_xor(s_i0[n], st);
                s_r1[n] += __shfl_xor(s_r1[n], st);
                s_i1[n] += __shfl_xor(s_i1[n], st);
            }
        }
        __syncthreads();                        // K-loop LDS dead -> reuse As as reduce buffer
        float4* red = (float4*)As;              // 64 slots x 16B = 1 KB
        if (fr == 0) {
#pragma unroll
            for (int n = 0; n < 4; ++n)
                red[wr * 32 + wc * 16 + n * 4 + fs] = make_float4(s_r0[n], s_i0[n], s_r1[n], s_i1[n]);
        }
        __syncthreads();
        if (tid < 32) {
            float4 a = red[tid], b2 = red[32 + tid];
            // sums[(b*NC+c)*256 + hp]; (b*NC+c) == tileM/128, hp == tileN/4 + slot
            sums[(long)(tileM >> 7) * 256 + (tileN >> 2) + tid] =
                make_float4(a.x + b2.x, a.y + b2.y, a.z + b2.z, a.w + b2.w);
        }
    } else {
        float* o = (float*)out;
#pragma unroll
        for (int n = 0; n < 4; ++n) {
            const int col0 = (int)tileN + wc * 64 + n * 16 + fs * 4;   // multiple of 4
            const float4 dv = *(const float4*)(e0 + col0);
#pragma unroll
            for (int m = 0; m < 4; ++m) {
                const long grow = tileM + wr * 64 + m * 16 + fr;
                const long idx = grow * N + col0;
                float u0, u1, u2, u3;
                if (e1b) {
                    ushort4 ub = *(const ushort4*)(e1b + idx);
                    u0 = bf2f(ub.x); u1 = bf2f(ub.y); u2 = bf2f(ub.z); u3 = bf2f(ub.w);
                } else {
                    float4 uf = *(const float4*)(e1 + idx);
                    u0 = uf.x; u1 = uf.y; u2 = uf.z; u3 = uf.w;
                }
                float4 st;
                st.x = acc[m][n][0] + dv.x * u0;
                st.y = acc[m][n][1] + dv.y * u1;
                st.z = acc[m][n][2] + dv.z * u2;
                st.w = acc[m][n][3] + dv.w * u3;
                *(float4*)(o + idx) = st;                              // 16B store, line-coalesced
            }
        }
    }
}

// ---------- scan: chunk sums fused into K1; k2b carries, k2ac local scan ----------

// k2b: exclusive scan over chunk sums -> carry (float4-per-hp layout)
__global__ __launch_bounds__(256) void k2b_carry(const float4* __restrict__ sums,
                                                 float4* __restrict__ carry,
                                                 const float* __restrict__ nu,
                                                 const float* __restrict__ theta) {
    const int gid = blockIdx.x * 256 + threadIdx.x;   // 8*256
    const int hp = gid & 255;
    const int b = gid >> 8;
    float lre0, lim0, lre1, lim1;
    lam_of(nu, theta, 2 * hp, lre0, lim0);
    lam_of(nu, theta, 2 * hp + 1, lre1, lim1);
    // lam^CL via 7 complex squarings (CL = 128 = 2^7)
    float p0r = lre0, p0i = lim0, p1r = lre1, p1i = lim1;
#pragma unroll
    for (int i = 0; i < 7; ++i) {
        float t0 = p0r * p0r - p0i * p0i; p0i = 2.f * p0r * p0i; p0r = t0;
        float t1 = p1r * p1r - p1i * p1i; p1i = 2.f * p1r * p1i; p1r = t1;
    }
    float c0r = 0.f, c0i = 0.f, c1r = 0.f, c1i = 0.f;
#pragma unroll
    for (int c = 0; c < NC; ++c) {
        long idx = ((long)b * NC + c) * 256 + hp;
        carry[idx] = make_float4(c0r, c0i, c1r, c1i);
        float4 s = sums[idx];
        float t0 = fmaf(p0r, c0r, fmaf(-p0i, c0i, s.x));
        c0i = fmaf(p0r, c0i, fmaf(p0i, c0r, s.y));
        c0r = t0;
        float t1 = fmaf(p1r, c1r, fmaf(-p1i, c1i, s.z));
        c1i = fmaf(p1r, c1i, fmaf(p1i, c1r, s.w));
        c1r = t1;
    }
}

// k2ac: fused local scan starting from carry -> final xs (one R+W pass, f32 state throughout)
__global__ __launch_bounds__(256) void k2ac_scan(ushort4* __restrict__ xs4,
                                                 const float4* __restrict__ carry,
                                                 const float* __restrict__ nu,
                                                 const float* __restrict__ theta) {
    const int gid = blockIdx.x * 256 + threadIdx.x;   // 8*32*256
    const int hp = gid & 255;
    const int c = (gid >> 8) & (NC - 1);
    const int b = gid >> 13;
    float lre0, lim0, lre1, lim1;
    lam_of(nu, theta, 2 * hp, lre0, lim0);
    lam_of(nu, theta, 2 * hp + 1, lre1, lim1);
    float4 cr = carry[((long)b * NC + c) * 256 + hp];
    float a0r = cr.x, a0i = cr.y, a1r = cr.z, a1i = cr.w;
    long base = ((long)b * T_LEN + (long)c * CL) * 256 + hp;
#pragma unroll 4
    for (int i = 0; i < CL; ++i) {
        ushort4 v = xs4[base + (long)i * 256];
        float u0r = bf2f(v.x), u0i = bf2f(v.y), u1r = bf2f(v.z), u1i = bf2f(v.w);
        float n0r = fmaf(lre0, a0r, fmaf(-lim0, a0i, u0r));
        float n0i = fmaf(lre0, a0i, fmaf(lim0, a0r, u0i));
        float n1r = fmaf(lre1, a1r, fmaf(-lim1, a1i, u1r));
        float n1i = fmaf(lre1, a1i, fmaf(lim1, a1r, u1i));
        a0r = n0r; a0i = n0i; a1r = n1r; a1i = n1i;
        ushort4 o;
        o.x = f2bf(a0r); o.y = f2bf(a0i); o.z = f2bf(a1r); o.w = f2bf(a1i);
        xs4[base + (long)i * 256] = o;
    }
}

extern "C" void kernel_launch(void* const* d_in, const int* in_sizes, int n_in,
                              void* d_out, int out_size, void* d_ws, size_t ws_size,
                              hipStream_t stream) {
    const float* x         = (const float*)d_in[0];
    const float* Bre       = (const float*)d_in[1];
    const float* Bim       = (const float*)d_in[2];
    const float* Cre       = (const float*)d_in[3];
    const float* Cim       = (const float*)d_in[4];
    const float* Dv        = (const float*)d_in[5];
    const float* nu        = (const float*)d_in[6];
    const float* theta     = (const float*)d_in[7];
    const float* gamma_log = (const float*)d_in[8];
    float* y = (float*)d_out;

    // ws layout:
    //   [0, 64MB)      xs (bf16 interleaved re,im)
    //   [64MB, 66MB)   region A: BT1 (0.5MB) -> CT (0.5MB, after K1)
    //   [66MB, 68MB)   region B: carry (1MB) | sums (1MB at +1MB)
    //   [68MB, 84MB)   xb (bf16 x) IF ws_size permits, else xb lives in d_out
    const size_t XS_BYTES  = (size_t)ROWS * H_DIM * 4;
    const size_t REG_BYTES = 2u * 1024 * 1024;
    const size_t XB_BYTES  = (size_t)ROWS * N_DIM * 2;
    unsigned short* xs_us = (unsigned short*)d_ws;
    ushort4* xs4   = (ushort4*)d_ws;
    char* regionA  = (char*)d_ws + XS_BYTES;
    char* regionB  = regionA + REG_BYTES;
    unsigned short* BT1 = (unsigned short*)regionA;
    unsigned short* CT  = (unsigned short*)regionA;
    float4*  carry = (float4*)regionB;
    float4*  sums  = (float4*)(regionB + 1024 * 1024);

    const bool xb_in_ws = ws_size >= XS_BYTES + 2 * REG_BYTES + XB_BYTES;
    unsigned short* xb = xb_in_ws ? (unsigned short*)(regionB + REG_BYTES)
                                  : (unsigned short*)d_out;

    conv_x<<<ROWS * N_DIM / 4 / 256, 256, 0, stream>>>((const float4*)x, (ushort4*)xb);
    conv_Bt<<<(N_DIM * H_DIM) / 256, 256, 0, stream>>>(Bre, Bim, BT1);

    // K1: xs = gamma * (u @ Bint) + fused chunk sums   M=32768 N=1024 K=256
    gemm_mfma<0><<<(ROWS / BM) * (1024 / BN), 256, 0, stream>>>(
        xb, BT1, ROWS, 1024, 256, gamma_log, nullptr, nullptr, nu, theta, sums, xs_us);

    // scan: k2s is fused into K1's epilogue; carries then fused local scan
    k2b_carry<<<(B_SZ * 256) / 256, 256, 0, stream>>>(sums, carry, nu, theta);
    k2ac_scan<<<(B_SZ * NC * 256) / 256, 256, 0, stream>>>(xs4, carry, nu, theta);

    // CT overwrites BT1 region (dead after K1)
    conv_Ct<<<(H_DIM * N_DIM) / 256, 256, 0, stream>>>(Cre, Cim, CT);

    // K3: y = Re(xs @ C) + D*u      M=32768 N=256 K=1024
    gemm_mfma<1><<<(ROWS / BM) * (256 / BN), 256, 0, stream>>>(
        xs_us, CT, ROWS, 256, 1024, Dv, x, xb_in_ws ? xb : nullptr, nullptr, nullptr, nullptr, y);
}